// Round 2
// baseline (1564.122 us; speedup 1.0000x reference)
//
#include <hip/hip_runtime.h>
#include <math.h>

#define IMG   224
#define NVIEWS 6
#define BATCH 16
#define NPTS  32768
#define KS    5
#define PLANE (IMG * IMG)   // 50176

struct ViewTrig {
    float sa[NVIEWS], ca[NVIEWS], se[NVIEWS], ce[NVIEWS];
    float off[KS];
};

// fp32 ops with contraction OFF — must round exactly like numpy's separate
// multiply/add ufuncs (hipcc default is -ffp-contract=fast, which would fuse
// x*ca - z*sa into fma and round differently, flipping pixel truncations).
__device__ __forceinline__ float fmul_(float a, float b) {
#pragma clang fp contract(off)
    return a * b;
}
__device__ __forceinline__ float fadd_(float a, float b) {
#pragma clang fp contract(off)
    return a + b;
}
__device__ __forceinline__ float fsub_(float a, float b) {
#pragma clang fp contract(off)
    return a - b;
}

// ---------------------------------------------------------------------------
// Kernel 1: per-(b,v) min/max of rotated depth z_fin, fp32 (exact same
// pipeline as the scatter kernel so the value set is identical).
// ---------------------------------------------------------------------------
__global__ __launch_bounds__(256) void minmax_kernel(
    const float* __restrict__ pts, float* __restrict__ zmm, ViewTrig vt)
{
    const int bv = blockIdx.x;            // 0..95
    const int b = bv / NVIEWS, v = bv % NVIEWS;
    const float sa = vt.sa[v], ca = vt.ca[v], se = vt.se[v], ce = vt.ce[v];
    const float* p = pts + (size_t)b * NPTS * 3;

    float zmin = INFINITY, zmax = -INFINITY;
    for (int n = threadIdx.x; n < NPTS; n += 256) {
        float x = p[n * 3 + 0];
        float y = p[n * 3 + 1];
        float z = p[n * 3 + 2];
        float zr = fadd_(fmul_(x, sa), fmul_(z, ca));
        float zf = fadd_(fmul_(y, se), fmul_(zr, ce));
        zmin = fminf(zmin, zf);
        zmax = fmaxf(zmax, zf);
    }
    for (int o = 32; o > 0; o >>= 1) {
        zmin = fminf(zmin, __shfl_down(zmin, o, 64));
        zmax = fmaxf(zmax, __shfl_down(zmax, o, 64));
    }
    __shared__ float smin[4], smax[4];
    const int wave = threadIdx.x >> 6;
    if ((threadIdx.x & 63) == 0) { smin[wave] = zmin; smax[wave] = zmax; }
    __syncthreads();
    if (threadIdx.x == 0) {
        for (int w = 1; w < 4; ++w) {
            zmin = fminf(zmin, smin[w]);
            zmax = fmaxf(zmax, smax[w]);
        }
        zmm[bv * 2 + 0] = zmin;
        zmm[bv * 2 + 1] = zmax;
    }
}

// ---------------------------------------------------------------------------
// Kernel 2: scatter-max splats, fp32 bit-faithful to the numpy reference.
// One thread per (b, n); inner loops over 6 views x 25 offsets.
// Feature > 0, so int-bit atomicMax == float max.
// ---------------------------------------------------------------------------
__global__ __launch_bounds__(256) void scatter_kernel(
    const float* __restrict__ pts, const float* __restrict__ zmm,
    float* __restrict__ out, ViewTrig vt)
{
    const int gid = blockIdx.x * blockDim.x + threadIdx.x;  // 0 .. BATCH*NPTS
    if (gid >= BATCH * NPTS) return;
    const int b = gid >> 15;              // / NPTS

    const float* p = pts + (size_t)gid * 3;
    const float x = p[0];
    const float y = p[1];
    const float z = p[2];

    for (int v = 0; v < NVIEWS; ++v) {
        const float sa = vt.sa[v], ca = vt.ca[v], se = vt.se[v], ce = vt.ce[v];
        const float xr = fsub_(fmul_(x, ca), fmul_(z, sa));
        const float zr = fadd_(fmul_(x, sa), fmul_(z, ca));
        const float yr = fsub_(fmul_(y, ce), fmul_(zr, se));
        const float zf = fadd_(fmul_(y, se), fmul_(zr, ce));

        const float zmin = zmm[(b * NVIEWS + v) * 2 + 0];
        const float zmax = zmm[(b * NVIEWS + v) * 2 + 1];
        // 0.3 + (0.7*(zf-zmin)) / ((zmax-zmin) + 1e-6), left-to-right fp32
        const float feat = fadd_(0.3f,
            __fdiv_rn(fmul_(0.7f, fsub_(zf, zmin)),
                      fadd_(fsub_(zmax, zmin), 1e-6f)));
        const int fb = __float_as_int(feat);

        // x-pixels for the 5 dx offsets (dx depends on j only)
        int px[KS]; bool okx[KS];
        #pragma unroll
        for (int j = 0; j < KS; ++j) {
            float cx = fadd_(xr, vt.off[j]);
            // ((cx + 1.0) * 0.5) * 223, truncate toward zero == astype(int32)
            int q = (int)fmul_(fmul_(fadd_(cx, 1.0f), 0.5f), 223.0f);
            px[j] = q;
            okx[j] = (q >= 0) && (q < IMG);
        }

        int* img = (int*)(out + (size_t)(b * NVIEWS + v) * 3 * PLANE);
        #pragma unroll
        for (int i = 0; i < KS; ++i) {
            float cy = fadd_(yr, vt.off[i]);
            int qy = (int)fmul_(fmul_(fadd_(cy, 1.0f), 0.5f), 223.0f);
            if (qy < 0 || qy >= IMG) continue;
            const int base = qy * IMG;
            #pragma unroll
            for (int j = 0; j < KS; ++j) {
                if (okx[j]) atomicMax(img + base + px[j], fb);
            }
        }
    }
}

// ---------------------------------------------------------------------------
// Kernel 3: replicate channel 0 -> channels 1,2 (float4 copies).
// ---------------------------------------------------------------------------
__global__ __launch_bounds__(256) void expand_kernel(float* __restrict__ out)
{
    const int gid = blockIdx.x * blockDim.x + threadIdx.x;  // 0 .. 96*12544
    const int nvec = PLANE / 4;                              // 12544
    if (gid >= BATCH * NVIEWS * nvec) return;
    const int pl = gid / nvec;
    const int r  = gid - pl * nvec;
    float4* basep = (float4*)(out + (size_t)pl * 3 * PLANE);
    float4 val = basep[r];
    basep[r + nvec]     = val;
    basep[r + 2 * nvec] = val;
}

extern "C" void kernel_launch(void* const* d_in, const int* in_sizes, int n_in,
                              void* d_out, int out_size, void* d_ws, size_t ws_size,
                              hipStream_t stream)
{
    const float* pts = (const float*)d_in[0];
    float* out = (float*)d_out;
    float* zmm = (float*)d_ws;   // 96*2 floats

    // fp32-faithful constants (JAX x32 semantics):
    //   a32 = fl32(60*v) * fl32(pi/180)   (fp32 multiply)
    //   trig = correctly-rounded fp32 of sin/cos(double(a32)) == glibc sinf/cosf
    ViewTrig vt;
    const float d2r = (float)(M_PI / 180.0);
    const float el_deg[NVIEWS] = {0.0f, 30.0f, -30.0f, 0.0f, 0.0f, 0.0f};
    for (int v = 0; v < NVIEWS; ++v) {
        float a = (float)(60 * v) * d2r;   // fp32 product, matches az*deg2rad
        float e = el_deg[v] * d2r;
        vt.sa[v] = (float)sin((double)a);
        vt.ca[v] = (float)cos((double)a);
        vt.se[v] = (float)sin((double)e);
        vt.ce[v] = (float)cos((double)e);
    }
    // linspace(-2/224, 2/224, 5) in fp32 is exactly {-s, -s/2, 0, s/2, s}
    // (all intermediate ops exact in fp32 for any linspace scheme).
    {
        const float s = (float)(2.0 / 224.0);
        vt.off[0] = -s;
        vt.off[1] = -0.5f * s;
        vt.off[2] = 0.0f;
        vt.off[3] = 0.5f * s;
        vt.off[4] = s;
    }

    // d_out is poisoned before every timed call: zero it (0x0 = 0.0f = atomicMax identity).
    hipMemsetAsync(d_out, 0, (size_t)out_size * sizeof(float), stream);

    minmax_kernel<<<BATCH * NVIEWS, 256, 0, stream>>>(pts, zmm, vt);

    const int nthreads = BATCH * NPTS;
    scatter_kernel<<<(nthreads + 255) / 256, 256, 0, stream>>>(pts, zmm, out, vt);

    const int nexp = BATCH * NVIEWS * (PLANE / 4);
    expand_kernel<<<(nexp + 255) / 256, 256, 0, stream>>>(out);
}

// Round 3
// 242.329 us; speedup vs baseline: 6.4545x; 6.4545x over previous
//
#include <hip/hip_runtime.h>
#include <math.h>
#include <limits.h>

#define IMG    224
#define NVIEWS 6
#define BATCH  16
#define NPTS   32768
#define KS     5
#define PLANE  (IMG * IMG)      // 50176
#define QROWS  56               // plane split into 4 quarters of 56 rows
#define TILE_ELEMS (QROWS * IMG) // 12544 ints = 50176 B LDS

struct ViewTrig {
    float sa[NVIEWS], ca[NVIEWS], se[NVIEWS], ce[NVIEWS];
    float off[KS];
};

// fp32 ops with contraction OFF — must round exactly like numpy's separate
// multiply/add ufuncs (hipcc default -ffp-contract=fast would fuse and flip
// pixel truncations).
__device__ __forceinline__ float fmul_(float a, float b) {
#pragma clang fp contract(off)
    return a * b;
}
__device__ __forceinline__ float fadd_(float a, float b) {
#pragma clang fp contract(off)
    return a + b;
}
__device__ __forceinline__ float fsub_(float a, float b) {
#pragma clang fp contract(off)
    return a - b;
}

// Order-preserving float->uint map (monotone for all finite floats).
__device__ __forceinline__ unsigned fmap_(float f) {
    unsigned b = __float_as_uint(f);
    return b ^ ((b >> 31) ? 0xFFFFFFFFu : 0x80000000u);
}
__device__ __forceinline__ float fmap_inv_(unsigned u) {
    unsigned b = (u & 0x80000000u) ? (u ^ 0x80000000u) : ~u;
    return __uint_as_float(b);
}

// ---------------------------------------------------------------------------
// Kernel 1: per-(b,v) min/max of z_fin. 96 (b,v) x 8 point-chunks = 768
// blocks; block-reduce then one mapped atomicMin/Max pair into d_ws.
// min/max are exact selections -> bit-identical to any reduction order.
// ---------------------------------------------------------------------------
__global__ __launch_bounds__(256) void minmax_kernel(
    const float* __restrict__ pts, unsigned* __restrict__ maxm,
    unsigned* __restrict__ minm, ViewTrig vt)
{
    const int blk = blockIdx.x;           // 0..767
    const int bv = blk >> 3, chunk = blk & 7;
    const int b = bv / NVIEWS, v = bv % NVIEWS;
    const float sa = vt.sa[v], se = vt.se[v], ce = vt.ce[v];
    const float ca = vt.ca[v];
    const float* p = pts + (size_t)b * NPTS * 3;

    float zmin = INFINITY, zmax = -INFINITY;
    const int n0 = chunk * (NPTS / 8);
    for (int k = 0; k < (NPTS / 8) / 256; ++k) {
        int n = n0 + k * 256 + threadIdx.x;
        float x = p[n * 3 + 0];
        float y = p[n * 3 + 1];
        float z = p[n * 3 + 2];
        float zr = fadd_(fmul_(x, sa), fmul_(z, ca));
        float zf = fadd_(fmul_(y, se), fmul_(zr, ce));
        zmin = fminf(zmin, zf);
        zmax = fmaxf(zmax, zf);
    }
    for (int o = 32; o > 0; o >>= 1) {
        zmin = fminf(zmin, __shfl_down(zmin, o, 64));
        zmax = fmaxf(zmax, __shfl_down(zmax, o, 64));
    }
    __shared__ float smin[4], smax[4];
    const int wave = threadIdx.x >> 6;
    if ((threadIdx.x & 63) == 0) { smin[wave] = zmin; smax[wave] = zmax; }
    __syncthreads();
    if (threadIdx.x == 0) {
        for (int w = 1; w < 4; ++w) {
            zmin = fminf(zmin, smin[w]);
            zmax = fmaxf(zmax, smax[w]);
        }
        atomicMax(&maxm[bv], fmap_(zmax));
        atomicMin(&minm[bv], fmap_(zmin));
    }
}

// ---------------------------------------------------------------------------
// Kernel 2: tiled render. One workgroup per (b, v, quarter-plane).
// Splat into a 56x224 LDS tile with LDS atomicMax (feat > 0, so int-bit
// max == float max); consecutive-duplicate dedup cuts 25 offsets to the
// <=9 unique pixels they actually cover. Then stream the tile to all 3
// channels of d_out (full coverage -> no memset / expand needed).
// ---------------------------------------------------------------------------
__global__ __launch_bounds__(256) void render_kernel(
    const float* __restrict__ pts, const unsigned* __restrict__ maxm,
    const unsigned* __restrict__ minm, float* __restrict__ out, ViewTrig vt)
{
    __shared__ int tile[TILE_ELEMS];

    const int wg = blockIdx.x;            // 0..383
    const int q  = wg & 3;
    const int bv = wg >> 2;
    const int b = bv / NVIEWS, v = bv % NVIEWS;
    const int row0 = q * QROWS;

    for (int i = threadIdx.x; i < TILE_ELEMS; i += 256) tile[i] = 0;
    __syncthreads();

    const float sa = vt.sa[v], ca = vt.ca[v], se = vt.se[v], ce = vt.ce[v];
    const float zmin = fmap_inv_(minm[bv]);
    const float zmax = fmap_inv_(maxm[bv]);
    const float denom = fadd_(fsub_(zmax, zmin), 1e-6f);
    const float* p = pts + (size_t)b * NPTS * 3;

    for (int n = threadIdx.x; n < NPTS; n += 256) {
        const float x = p[n * 3 + 0];
        const float y = p[n * 3 + 1];
        const float z = p[n * 3 + 2];

        const float xr = fsub_(fmul_(x, ca), fmul_(z, sa));
        const float zr = fadd_(fmul_(x, sa), fmul_(z, ca));
        const float yr = fsub_(fmul_(y, ce), fmul_(zr, se));
        const float zf = fadd_(fmul_(y, se), fmul_(zr, ce));

        const float feat = fadd_(0.3f,
            __fdiv_rn(fmul_(0.7f, fsub_(zf, zmin)), denom));
        const int fb = __float_as_int(feat);

        int px[KS];
        #pragma unroll
        for (int j = 0; j < KS; ++j) {
            float cx = fadd_(xr, vt.off[j]);
            px[j] = (int)fmul_(fmul_(fadd_(cx, 1.0f), 0.5f), 223.0f);
        }
        int qy[KS];
        #pragma unroll
        for (int i = 0; i < KS; ++i) {
            float cy = fadd_(yr, vt.off[i]);
            qy[i] = (int)fmul_(fmul_(fadd_(cy, 1.0f), 0.5f), 223.0f);
        }

        int prevy = INT_MIN;
        #pragma unroll
        for (int i = 0; i < KS; ++i) {
            const int ry = qy[i];
            if (ry == prevy) continue;     // qy non-decreasing -> full dedup
            prevy = ry;
            const int lr = ry - row0;
            if (lr < 0 || lr >= QROWS) continue;  // includes py bounds check
            const int lbase = lr * IMG;
            int prevx = INT_MIN;
            #pragma unroll
            for (int j = 0; j < KS; ++j) {
                const int cx = px[j];
                if (cx == prevx) continue;
                prevx = cx;
                if (cx < 0 || cx >= IMG) continue;
                atomicMax(&tile[lbase + cx], fb);
            }
        }
    }
    __syncthreads();

    // Write the tile to channels 0,1,2 of this (b,v) plane (float4 stores).
    float* dst = out + ((size_t)bv * 3) * PLANE + (size_t)row0 * IMG;
    const float4* src = (const float4*)tile;
    #pragma unroll
    for (int c = 0; c < 3; ++c) {
        float4* d4 = (float4*)(dst + (size_t)c * PLANE);
        for (int i = threadIdx.x; i < TILE_ELEMS / 4; i += 256)
            d4[i] = src[i];
    }
}

extern "C" void kernel_launch(void* const* d_in, const int* in_sizes, int n_in,
                              void* d_out, int out_size, void* d_ws, size_t ws_size,
                              hipStream_t stream)
{
    const float* pts = (const float*)d_in[0];
    float* out = (float*)d_out;
    unsigned* maxm = (unsigned*)d_ws;                 // 96 uints
    unsigned* minm = (unsigned*)d_ws + BATCH * NVIEWS; // 96 uints

    // fp32-faithful constants (JAX x32 semantics), same as the passing round.
    ViewTrig vt;
    const float d2r = (float)(M_PI / 180.0);
    const float el_deg[NVIEWS] = {0.0f, 30.0f, -30.0f, 0.0f, 0.0f, 0.0f};
    for (int v = 0; v < NVIEWS; ++v) {
        float a = (float)(60 * v) * d2r;
        float e = el_deg[v] * d2r;
        vt.sa[v] = (float)sin((double)a);
        vt.ca[v] = (float)cos((double)a);
        vt.se[v] = (float)sin((double)e);
        vt.ce[v] = (float)cos((double)e);
    }
    {
        const float s = (float)(2.0 / 224.0);
        vt.off[0] = -s;
        vt.off[1] = -0.5f * s;
        vt.off[2] = 0.0f;
        vt.off[3] = 0.5f * s;
        vt.off[4] = s;
    }

    // Init mapped min/max identities (ws is poisoned before every call).
    hipMemsetAsync(maxm, 0x00, BATCH * NVIEWS * sizeof(unsigned), stream);
    hipMemsetAsync(minm, 0xFF, BATCH * NVIEWS * sizeof(unsigned), stream);

    minmax_kernel<<<BATCH * NVIEWS * 8, 256, 0, stream>>>(pts, maxm, minm, vt);
    render_kernel<<<BATCH * NVIEWS * 4, 256, 0, stream>>>(pts, maxm, minm, out, vt);
}

// Round 4
// 124.508 us; speedup vs baseline: 12.5624x; 1.9463x over previous
//
#include <hip/hip_runtime.h>
#include <math.h>

#define IMG    224
#define NVIEWS 6
#define BATCH  16
#define NPTS   32768
#define NCHUNK 8
#define CHUNK  (NPTS / NCHUNK)   // 4096
#define PLANE  (IMG * IMG)       // 50176
#define QROWS  56                // plane split into 4 quarters of 56 rows
#define TILE_ELEMS (QROWS * IMG) // 12544 ints = 50176 B LDS

struct ViewTrig {
    float sa[NVIEWS], ca[NVIEWS], se[NVIEWS], ce[NVIEWS];
    float off0, off4;            // only the extreme splat offsets are needed
};

// fp32 ops with contraction OFF — must round exactly like numpy's separate
// multiply/add ufuncs (hipcc default -ffp-contract=fast would fuse and flip
// pixel truncations).
__device__ __forceinline__ float fmul_(float a, float b) {
#pragma clang fp contract(off)
    return a * b;
}
__device__ __forceinline__ float fadd_(float a, float b) {
#pragma clang fp contract(off)
    return a + b;
}
__device__ __forceinline__ float fsub_(float a, float b) {
#pragma clang fp contract(off)
    return a - b;
}
// ((c + 1) * 0.5) * 223, truncate toward zero == astype(int32)
__device__ __forceinline__ int pix_(float c) {
    return (int)fmul_(fmul_(fadd_(c, 1.0f), 0.5f), 223.0f);
}

// ---------------------------------------------------------------------------
// Kernel 1: per-(b,chunk) min/max of z_fin for ALL 6 views in one pass.
// 128 blocks; partials to d_ws (no atomics, no memset init needed).
// min/max are exact selections -> bit-identical to any reduction order.
// ---------------------------------------------------------------------------
__global__ __launch_bounds__(256) void minmax_kernel(
    const float* __restrict__ pts, float* __restrict__ mm, ViewTrig vt)
{
    const int blk = blockIdx.x;           // 0..127
    const int b = blk >> 3, chunk = blk & 7;
    const float* p = pts + ((size_t)b * NPTS + (size_t)chunk * CHUNK) * 3;

    float zmin[NVIEWS], zmax[NVIEWS];
    #pragma unroll
    for (int v = 0; v < NVIEWS; ++v) { zmin[v] = INFINITY; zmax[v] = -INFINITY; }

    for (int n = threadIdx.x; n < CHUNK; n += 256) {
        const float x = p[n * 3 + 0];
        const float y = p[n * 3 + 1];
        const float z = p[n * 3 + 2];
        #pragma unroll
        for (int v = 0; v < NVIEWS; ++v) {
            float zr = fadd_(fmul_(x, vt.sa[v]), fmul_(z, vt.ca[v]));
            float zf = fadd_(fmul_(y, vt.se[v]), fmul_(zr, vt.ce[v]));
            zmin[v] = fminf(zmin[v], zf);
            zmax[v] = fmaxf(zmax[v], zf);
        }
    }
    #pragma unroll
    for (int v = 0; v < NVIEWS; ++v)
        for (int o = 32; o > 0; o >>= 1) {
            zmin[v] = fminf(zmin[v], __shfl_down(zmin[v], o, 64));
            zmax[v] = fmaxf(zmax[v], __shfl_down(zmax[v], o, 64));
        }
    __shared__ float smin[NVIEWS][4], smax[NVIEWS][4];
    const int wave = threadIdx.x >> 6;
    if ((threadIdx.x & 63) == 0) {
        #pragma unroll
        for (int v = 0; v < NVIEWS; ++v) { smin[v][wave] = zmin[v]; smax[v][wave] = zmax[v]; }
    }
    __syncthreads();
    if (threadIdx.x < NVIEWS) {
        const int v = threadIdx.x;
        float mn = smin[v][0], mx = smax[v][0];
        for (int w = 1; w < 4; ++w) { mn = fminf(mn, smin[v][w]); mx = fmaxf(mx, smax[v][w]); }
        mm[((size_t)blk * NVIEWS + v) * 2 + 0] = mn;
        mm[((size_t)blk * NVIEWS + v) * 2 + 1] = mx;
    }
}

// ---------------------------------------------------------------------------
// Kernel 2: tiled render. One 1024-thread WG per (b, v, quarter-plane).
// The 25-offset splat footprint is exactly the integer rectangle
// [pix(xr+off0)..pix(xr+off4)] x [pix(yr+off0)..pix(yr+off4)] clamped to
// bounds (px/py non-decreasing with step <= 1 -> intermediate values all
// hit; x/y validity independent -> Cartesian product). LDS atomicMax
// (feat > 0 -> int-bit max == float max), then tile streamed to all 3
// channels (full coverage -> no memset / expand).
// __launch_bounds__(1024, 8): VGPR <= 64 so 2 WGs (32 waves) fit per CU.
// ---------------------------------------------------------------------------
__global__ __launch_bounds__(1024, 8) void render_kernel(
    const float* __restrict__ pts, const float* __restrict__ mm,
    float* __restrict__ out, ViewTrig vt)
{
    __shared__ int tile[TILE_ELEMS];

    const int wg = blockIdx.x;            // 0..383
    const int q  = wg & 3;
    const int bv = wg >> 2;
    const int b = bv / NVIEWS, v = bv - b * NVIEWS;
    const int row0 = q * QROWS;

    for (int i = threadIdx.x; i < TILE_ELEMS; i += 1024) tile[i] = 0;

    // Reduce the 8 chunk partials for this (b,v) — uniform scalar loads.
    float zmin = INFINITY, zmax = -INFINITY;
    #pragma unroll
    for (int c = 0; c < NCHUNK; ++c) {
        zmin = fminf(zmin, mm[(((size_t)b * NCHUNK + c) * NVIEWS + v) * 2 + 0]);
        zmax = fmaxf(zmax, mm[(((size_t)b * NCHUNK + c) * NVIEWS + v) * 2 + 1]);
    }
    __syncthreads();

    const float sa = vt.sa[v], ca = vt.ca[v], se = vt.se[v], ce = vt.ce[v];
    const float denom = fadd_(fsub_(zmax, zmin), 1e-6f);
    const float* p = pts + (size_t)b * NPTS * 3;

    for (int n = threadIdx.x; n < NPTS; n += 1024) {
        const float x = p[n * 3 + 0];
        const float y = p[n * 3 + 1];
        const float z = p[n * 3 + 2];

        const float xr = fsub_(fmul_(x, ca), fmul_(z, sa));
        const float zr = fadd_(fmul_(x, sa), fmul_(z, ca));
        const float yr = fsub_(fmul_(y, ce), fmul_(zr, se));
        const float zf = fadd_(fmul_(y, se), fmul_(zr, ce));

        const int fb = __float_as_int(fadd_(0.3f,
            __fdiv_rn(fmul_(0.7f, fsub_(zf, zmin)), denom)));

        const int y0i = max(pix_(fadd_(yr, vt.off0)), row0);
        const int y1i = min(pix_(fadd_(yr, vt.off4)), row0 + QROWS - 1);
        if (y0i > y1i) continue;
        const int x0i = max(pix_(fadd_(xr, vt.off0)), 0);
        const int x1i = min(pix_(fadd_(xr, vt.off4)), IMG - 1);

        for (int ry = y0i; ry <= y1i; ++ry) {
            const int base = (ry - row0) * IMG;
            for (int cx = x0i; cx <= x1i; ++cx)
                atomicMax(&tile[base + cx], fb);
        }
    }
    __syncthreads();

    // Stream the tile to channels 0,1,2 of this (b,v) plane (float4 stores).
    float* dst = out + ((size_t)bv * 3) * PLANE + (size_t)row0 * IMG;
    const float4* src = (const float4*)tile;
    #pragma unroll
    for (int c = 0; c < 3; ++c) {
        float4* d4 = (float4*)(dst + (size_t)c * PLANE);
        for (int i = threadIdx.x; i < TILE_ELEMS / 4; i += 1024)
            d4[i] = src[i];
    }
}

extern "C" void kernel_launch(void* const* d_in, const int* in_sizes, int n_in,
                              void* d_out, int out_size, void* d_ws, size_t ws_size,
                              hipStream_t stream)
{
    const float* pts = (const float*)d_in[0];
    float* out = (float*)d_out;
    float* mm = (float*)d_ws;   // 128 * 6 * 2 floats = 6 KB partial min/max

    // fp32-faithful constants (JAX x32 semantics), same as the passing rounds.
    ViewTrig vt;
    const float d2r = (float)(M_PI / 180.0);
    const float el_deg[NVIEWS] = {0.0f, 30.0f, -30.0f, 0.0f, 0.0f, 0.0f};
    for (int v = 0; v < NVIEWS; ++v) {
        float a = (float)(60 * v) * d2r;
        float e = el_deg[v] * d2r;
        vt.sa[v] = (float)sin((double)a);
        vt.ca[v] = (float)cos((double)a);
        vt.se[v] = (float)sin((double)e);
        vt.ce[v] = (float)cos((double)e);
    }
    {
        const float s = (float)(2.0 / 224.0);  // linspace end points, exact in fp32
        vt.off0 = -s;
        vt.off4 = s;
    }

    minmax_kernel<<<BATCH * NCHUNK, 256, 0, stream>>>(pts, mm, vt);
    render_kernel<<<BATCH * NVIEWS * 4, 1024, 0, stream>>>(pts, mm, out, vt);
}

// Round 5
// 105.539 us; speedup vs baseline: 14.8204x; 1.1797x over previous
//
#include <hip/hip_runtime.h>
#include <math.h>

#define IMG    224
#define NVIEWS 6
#define BATCH  16
#define NPTS   32768
#define PLANE  (IMG * IMG)       // 50176
#define HROWS  112               // half-plane tile
#define TILE_ELEMS (HROWS * IMG) // 25088 ints = 100352 B dynamic LDS
#define NTHREADS 1024
#define NWG (BATCH * NVIEWS * 2) // 192

struct ViewTrig {
    float sa[NVIEWS], ca[NVIEWS], se[NVIEWS], ce[NVIEWS];
    float off0, off4;            // extreme splat offsets (footprint rectangle)
};

// fp32 ops with contraction OFF — these feed the pixel truncation and must
// round exactly like numpy's separate mul/add ufuncs (default -ffp-contract=fast
// would fuse and flip truncations).
__device__ __forceinline__ float fmul_(float a, float b) {
#pragma clang fp contract(off)
    return a * b;
}
__device__ __forceinline__ float fadd_(float a, float b) {
#pragma clang fp contract(off)
    return a + b;
}
__device__ __forceinline__ float fsub_(float a, float b) {
#pragma clang fp contract(off)
    return a - b;
}
// ((c + 1) * 0.5) * 223, truncate toward zero == astype(int32)
__device__ __forceinline__ int pix_(float c) {
    return (int)fmul_(fmul_(fadd_(c, 1.0f), 0.5f), 223.0f);
}

// ---------------------------------------------------------------------------
// Fused kernel: one 1024-thread WG per (b, v, half-plane).
//  pass 0: zero the 112x224 LDS tile
//  pass 1: block-local zmin/zmax of z_fin over ALL points (relaxed math OK:
//          zmin/zmax only affect the feature VALUE, tolerance 2e-2)
//  pass 2: splat. Footprint of the 25 offsets == integer rectangle
//          [pix(xr+off0)..pix(xr+off4)] x [pix(yr+off0)..pix(yr+off4)]
//          (px/py non-decreasing, step <= 1, x/y validity independent),
//          realized as 9 predicated LDS atomicMax (feat > 0 -> int-bit
//          max == float max). feat = fmaf(zf, scale, bias), no division.
//  pass 3: stream tile to channels 0,1,2 (full coverage -> no memset).
// ---------------------------------------------------------------------------
__global__ __launch_bounds__(NTHREADS, 4) void render_kernel(
    const float* __restrict__ pts, float* __restrict__ out, ViewTrig vt)
{
    extern __shared__ __align__(16) int tile[];
    __shared__ float smin[NTHREADS / 64], smax[NTHREADS / 64];

    const int wg = blockIdx.x;            // 0..191
    const int h  = wg & 1;
    const int bv = wg >> 1;
    const int b = bv / NVIEWS, v = bv - b * NVIEWS;
    const int row0 = h * HROWS;

    const float sa = vt.sa[v], ca = vt.ca[v], se = vt.se[v], ce = vt.ce[v];
    const float* p = pts + (size_t)b * NPTS * 3;

    for (int i = threadIdx.x; i < TILE_ELEMS; i += NTHREADS) tile[i] = 0;

    // ---- pass 1: plane min/max of z_fin (relaxed fp ok) ----
    float zmin = INFINITY, zmax = -INFINITY;
    for (int n = threadIdx.x; n < NPTS; n += NTHREADS) {
        const float x = p[n * 3 + 0];
        const float y = p[n * 3 + 1];
        const float z = p[n * 3 + 2];
        const float zr = fmaf(z, ca, x * sa);
        const float zf = fmaf(zr, ce, y * se);
        zmin = fminf(zmin, zf);
        zmax = fmaxf(zmax, zf);
    }
    for (int o = 32; o > 0; o >>= 1) {
        zmin = fminf(zmin, __shfl_down(zmin, o, 64));
        zmax = fmaxf(zmax, __shfl_down(zmax, o, 64));
    }
    const int wave = threadIdx.x >> 6;
    if ((threadIdx.x & 63) == 0) { smin[wave] = zmin; smax[wave] = zmax; }
    __syncthreads();
    if (threadIdx.x == 0) {
        float mn = smin[0], mx = smax[0];
        for (int w = 1; w < NTHREADS / 64; ++w) {
            mn = fminf(mn, smin[w]);
            mx = fmaxf(mx, smax[w]);
        }
        smin[0] = mn; smax[0] = mx;
    }
    __syncthreads();
    zmin = smin[0]; zmax = smax[0];
    // feat = 0.3 + 0.7*(zf-zmin)/denom  ==  zf*scale + bias   (err ~1e-6 << 2e-2)
    const float scale = 0.7f / ((zmax - zmin) + 1e-6f);
    const float bias  = 0.3f - zmin * scale;
    __syncthreads();   // tile zero-init complete before atomics

    // ---- pass 2: splat ----
    for (int n = threadIdx.x; n < NPTS; n += NTHREADS) {
        const float x = p[n * 3 + 0];
        const float y = p[n * 3 + 1];
        const float z = p[n * 3 + 2];

        // strict fp32 chain -> pixel coordinates (bit-exact vs numpy)
        const float zr = fadd_(fmul_(x, sa), fmul_(z, ca));
        const float yr = fsub_(fmul_(y, ce), fmul_(zr, se));
        const float xr = fsub_(fmul_(x, ca), fmul_(z, sa));

        const int y0i = max(pix_(fadd_(yr, vt.off0)), row0);
        const int y1i = min(pix_(fadd_(yr, vt.off4)), row0 + HROWS - 1);
        const int x0i = max(pix_(fadd_(xr, vt.off0)), 0);
        const int x1i = min(pix_(fadd_(xr, vt.off4)), IMG - 1);

        // relaxed feature value
        const float zf = fmaf(zr, ce, y * se);
        const int fb = __float_as_int(fmaf(zf, scale, bias));

        #pragma unroll
        for (int dy = 0; dy < 3; ++dy) {
            const int ry = y0i + dy;
            const bool yok = (ry <= y1i);
            const int base = (ry - row0) * IMG;   // >= 0 (y0i >= row0)
            #pragma unroll
            for (int dx = 0; dx < 3; ++dx) {
                const int cx = x0i + dx;
                if (yok && (cx <= x1i)) atomicMax(&tile[base + cx], fb);
            }
        }
    }
    __syncthreads();

    // ---- pass 3: tile -> channels 0,1,2 (float4 stores) ----
    float* dst = out + ((size_t)bv * 3) * PLANE + (size_t)row0 * IMG;
    const float4* src = (const float4*)tile;
    #pragma unroll
    for (int c = 0; c < 3; ++c) {
        float4* d4 = (float4*)(dst + (size_t)c * PLANE);
        for (int i = threadIdx.x; i < TILE_ELEMS / 4; i += NTHREADS)
            d4[i] = src[i];
    }
}

extern "C" void kernel_launch(void* const* d_in, const int* in_sizes, int n_in,
                              void* d_out, int out_size, void* d_ws, size_t ws_size,
                              hipStream_t stream)
{
    const float* pts = (const float*)d_in[0];
    float* out = (float*)d_out;

    // fp32-faithful constants (JAX x32 semantics), same as the passing rounds.
    ViewTrig vt;
    const float d2r = (float)(M_PI / 180.0);
    const float el_deg[NVIEWS] = {0.0f, 30.0f, -30.0f, 0.0f, 0.0f, 0.0f};
    for (int v = 0; v < NVIEWS; ++v) {
        float a = (float)(60 * v) * d2r;
        float e = el_deg[v] * d2r;
        vt.sa[v] = (float)sin((double)a);
        vt.ca[v] = (float)cos((double)a);
        vt.se[v] = (float)sin((double)e);
        vt.ce[v] = (float)cos((double)e);
    }
    {
        const float s = (float)(2.0 / 224.0);  // linspace end points, exact in fp32
        vt.off0 = -s;
        vt.off4 = s;
    }

    // Opt in to >64KB dynamic LDS (160 KiB/CU on gfx950). Idempotent, not a
    // stream op — graph-capture safe.
    static bool attr_set = false;
    (void)attr_set;
    hipFuncSetAttribute(reinterpret_cast<const void*>(render_kernel),
                        hipFuncAttributeMaxDynamicSharedMemorySize,
                        TILE_ELEMS * (int)sizeof(int));

    render_kernel<<<NWG, NTHREADS, TILE_ELEMS * sizeof(int), stream>>>(pts, out, vt);
}

// Round 7
// 91.542 us; speedup vs baseline: 17.0865x; 1.1529x over previous
//
#include <hip/hip_runtime.h>
#include <math.h>

#define IMG    224
#define NVIEWS 6
#define BATCH  16
#define NPTS   32768
#define PLANE  (IMG * IMG)       // 50176
#define HROWS  112               // half-plane tile
#define TILE_ELEMS (HROWS * IMG) // 25088 ints = 100352 B dynamic LDS
#define NTHREADS 1024
#define NWG (BATCH * NVIEWS * 2) // 192

typedef float fx4 __attribute__((ext_vector_type(4)));   // native vec for nontemporal

struct ViewTrig {
    float sa[NVIEWS], ca[NVIEWS], se[NVIEWS], ce[NVIEWS];
    float off0, off4;            // extreme splat offsets (footprint rectangle)
};

// fp32 ops with contraction OFF — these feed the pixel truncation and must
// round exactly like numpy's separate mul/add ufuncs.
__device__ __forceinline__ float fmul_(float a, float b) {
#pragma clang fp contract(off)
    return a * b;
}
__device__ __forceinline__ float fadd_(float a, float b) {
#pragma clang fp contract(off)
    return a + b;
}
__device__ __forceinline__ float fsub_(float a, float b) {
#pragma clang fp contract(off)
    return a - b;
}
// ((c + 1) * 0.5) * 223, truncate toward zero == astype(int32)
__device__ __forceinline__ int pix_(float c) {
    return (int)fmul_(fmul_(fadd_(c, 1.0f), 0.5f), 223.0f);
}

// Order-preserving float->uint map (monotone over all finite floats).
// Any zf here maps to a value >> 0, so 0 is a safe "empty" sentinel.
__device__ __forceinline__ unsigned fmap_(float f) {
    unsigned b = __float_as_uint(f);
    return b ^ ((unsigned)((int)b >> 31) | 0x80000000u);
}
__device__ __forceinline__ float fmap_inv_(unsigned u) {
    unsigned b = (u & 0x80000000u) ? (u ^ 0x80000000u) : ~u;
    return __uint_as_float(b);
}

// ---------------------------------------------------------------------------
// Fully fused, single-scan render. One 1024-thread WG per (b, v, half-plane).
//
// Monotonicity trick: feat = zf*scale + bias with scale > 0, so
// max(feat) == f(max(zf)). We scatter-max fmap(zf) (order-preserving uint)
// during the SAME pass that accumulates zmin/zmax, then apply scale/bias in
// the epilogue. One point scan instead of two, no barrier between phases;
// VALU, VMEM, and the LDS-atomic pipe overlap.
//
// XCD swizzle: bid&7 == XCD (8 XCDs, round-robin dispatch); XCD x hosts
// batches {x, x+8} only, so each batch's 393 KB of points is fetched into
// exactly one XCD's L2 (perf heuristic only — correctness never depends on
// the mapping).
// ---------------------------------------------------------------------------
__global__ __launch_bounds__(NTHREADS, 4) void render_kernel(
    const float* __restrict__ pts, float* __restrict__ out, ViewTrig vt)
{
    extern __shared__ __align__(16) unsigned tile[];
    __shared__ float smin[NTHREADS / 64], smax[NTHREADS / 64];

    // XCD-aware decode: xcd = bid&7, slot = bid>>3 (0..23)
    const int bid  = blockIdx.x;
    const int xcd  = bid & 7;
    const int slot = bid >> 3;
    const int hi   = (slot >= 12) ? 1 : 0;
    const int b    = xcd + 8 * hi;
    const int vh   = slot - 12 * hi;
    const int v    = vh >> 1;
    const int h    = vh & 1;
    const int bv   = b * NVIEWS + v;
    const int row0 = h * HROWS;

    const float sa = vt.sa[v], ca = vt.ca[v], se = vt.se[v], ce = vt.ce[v];
    const float off0 = vt.off0, off4 = vt.off4;
    const float4* p4 = (const float4*)(pts + (size_t)b * NPTS * 3);

    // zero tile (int4 stores)
    {
        int4* t4 = (int4*)tile;
        for (int i = threadIdx.x; i < TILE_ELEMS / 4; i += NTHREADS)
            t4[i] = make_int4(0, 0, 0, 0);
    }
    __syncthreads();

    // ---- single fused pass: minmax + splat ----
    float zmin = INFINITY, zmax = -INFINITY;

    auto do_point = [&](float x, float y, float z) {
        // strict fp32 chain -> pixel coordinates (bit-exact vs numpy)
        const float zr = fadd_(fmul_(x, sa), fmul_(z, ca));
        const float yr = fsub_(fmul_(y, ce), fmul_(zr, se));
        const float xr = fsub_(fmul_(x, ca), fmul_(z, sa));

        const int y0i = max(pix_(fadd_(yr, off0)), row0);
        const int y1i = min(pix_(fadd_(yr, off4)), row0 + HROWS - 1);
        const int x0i = max(pix_(fadd_(xr, off0)), 0);
        const int x1i = min(pix_(fadd_(xr, off4)), IMG - 1);

        // relaxed depth value (feeds both minmax and the splat payload)
        const float zf = fmaf(zr, ce, y * se);
        zmin = fminf(zmin, zf);
        zmax = fmaxf(zmax, zf);
        const unsigned fz = fmap_(zf);

        #pragma unroll
        for (int dy = 0; dy < 3; ++dy) {
            const int ry = y0i + dy;
            const bool yok = (ry <= y1i);
            const int base = (ry - row0) * IMG;
            #pragma unroll
            for (int dx = 0; dx < 3; ++dx) {
                const int cx = x0i + dx;
                if (yok && (cx <= x1i)) atomicMax(&tile[base + cx], fz);
            }
        }
    };

    #pragma unroll
    for (int k = 0; k < NPTS / (4 * NTHREADS); ++k) {   // 8 iterations
        const int g = threadIdx.x + k * NTHREADS;       // 4-point group index
        const float4 A = p4[3 * g + 0];
        const float4 B = p4[3 * g + 1];
        const float4 C = p4[3 * g + 2];
        do_point(A.x, A.y, A.z);
        do_point(A.w, B.x, B.y);
        do_point(B.z, B.w, C.x);
        do_point(C.y, C.z, C.w);
    }

    // ---- block reduce zmin/zmax ----
    for (int o = 32; o > 0; o >>= 1) {
        zmin = fminf(zmin, __shfl_down(zmin, o, 64));
        zmax = fmaxf(zmax, __shfl_down(zmax, o, 64));
    }
    const int wave = threadIdx.x >> 6;
    if ((threadIdx.x & 63) == 0) { smin[wave] = zmin; smax[wave] = zmax; }
    __syncthreads();   // also orders all LDS atomics before the epilogue
    if (threadIdx.x == 0) {
        float mn = smin[0], mx = smax[0];
        for (int w = 1; w < NTHREADS / 64; ++w) {
            mn = fminf(mn, smin[w]);
            mx = fmaxf(mx, smax[w]);
        }
        smin[0] = mn; smax[0] = mx;
    }
    __syncthreads();
    // feat = 0.3 + 0.7*(zf-zmin)/denom == zf*scale + bias  (err ~1e-6 << 2e-2)
    const float scale = 0.7f / ((smax[0] - smin[0]) + 1e-6f);
    const float bias  = 0.3f - smin[0] * scale;

    // ---- epilogue: tile -> feat -> channels 0,1,2 (non-temporal fx4) ----
    float* dst = out + ((size_t)bv * 3) * PLANE + (size_t)row0 * IMG;
    const uint4* src = (const uint4*)tile;
    for (int i = threadIdx.x; i < TILE_ELEMS / 4; i += NTHREADS) {
        const uint4 u = src[i];
        fx4 f;
        f.x = (u.x == 0u) ? 0.0f : fmaf(fmap_inv_(u.x), scale, bias);
        f.y = (u.y == 0u) ? 0.0f : fmaf(fmap_inv_(u.y), scale, bias);
        f.z = (u.z == 0u) ? 0.0f : fmaf(fmap_inv_(u.z), scale, bias);
        f.w = (u.w == 0u) ? 0.0f : fmaf(fmap_inv_(u.w), scale, bias);
        #pragma unroll
        for (int c = 0; c < 3; ++c)
            __builtin_nontemporal_store(f, (fx4*)(dst + (size_t)c * PLANE) + i);
    }
}

extern "C" void kernel_launch(void* const* d_in, const int* in_sizes, int n_in,
                              void* d_out, int out_size, void* d_ws, size_t ws_size,
                              hipStream_t stream)
{
    const float* pts = (const float*)d_in[0];
    float* out = (float*)d_out;

    // fp32-faithful constants (JAX x32 semantics), same as the passing rounds.
    ViewTrig vt;
    const float d2r = (float)(M_PI / 180.0);
    const float el_deg[NVIEWS] = {0.0f, 30.0f, -30.0f, 0.0f, 0.0f, 0.0f};
    for (int v = 0; v < NVIEWS; ++v) {
        float a = (float)(60 * v) * d2r;
        float e = el_deg[v] * d2r;
        vt.sa[v] = (float)sin((double)a);
        vt.ca[v] = (float)cos((double)a);
        vt.se[v] = (float)sin((double)e);
        vt.ce[v] = (float)cos((double)e);
    }
    {
        const float s = (float)(2.0 / 224.0);  // linspace end points, exact in fp32
        vt.off0 = -s;
        vt.off4 = s;
    }

    // Opt in to >64KB dynamic LDS (160 KiB/CU on gfx950). Graph-capture safe.
    (void)hipFuncSetAttribute(reinterpret_cast<const void*>(render_kernel),
                              hipFuncAttributeMaxDynamicSharedMemorySize,
                              TILE_ELEMS * (int)sizeof(int));

    render_kernel<<<NWG, NTHREADS, TILE_ELEMS * sizeof(int), stream>>>(pts, out, vt);
}